// Round 6
// baseline (188.562 us; speedup 1.0000x reference)
//
#include <hip/hip_runtime.h>
#include <hip/hip_bf16.h>

// Problem constants
#define BSZ 64
#define LL  64
#define SS  63
#define AMB 32
#define HH  128
#define EE  300
#define MLPN 1024
#define GG  640      // 5*H
#define K2  256      // 2*H
#define PP  127      // L+S
#define CROW 272     // chart LDS row stride in shorts (544 B; bank spread)

typedef __attribute__((ext_vector_type(8))) short short8;   // 8 bf16 MFMA A/B frag
typedef __attribute__((ext_vector_type(4))) float f32x4;

__device__ __forceinline__ float sigf(float x) { return 1.f / (1.f + __expf(-x)); }

__device__ __forceinline__ unsigned short f2bf(float x) {
    unsigned int u = __float_as_uint(x);
    u += 0x7fffu + ((u >> 16) & 1u);      // RNE
    return (unsigned short)(u >> 16);
}
__device__ __forceinline__ float bf2f(short x) {
    return __uint_as_float(((unsigned)(unsigned short)x) << 16);
}

// ---------------------------------------------------------------------------
// Prep: pack W -> WTB, U -> UTB as bf16 B-operand fragments of
// mfma_f32_16x16x32_bf16:
//   XTB[((n*KSTEPS + kk)*64 + lane)*8 + j] = X[g][k],
//   g = n*16 + (lane&15), k = kk*32 + (lane>>4)*8 + j
// ---------------------------------------------------------------------------
#define PW 25600     // WTB short8 items: 40 ntiles * 10 ksteps * 64 lanes
#define PU 20480     // UTB short8 items: 40 * 8 * 64
__global__ void __launch_bounds__(256) prep_kernel(
        const float* __restrict__ W, const float* __restrict__ U,
        short* __restrict__ WTB, short* __restrict__ UTB) {
    int idx = blockIdx.x * 256 + threadIdx.x;
    if (idx < PW) {
        int lane = idx & 63, r = idx >> 6;
        int kk = r % 10, n = r / 10;
        int g = n * 16 + (lane & 15);
        int k0 = kk * 32 + ((lane >> 4) << 3);
        const float* src = W + (size_t)g * EE + k0;
        float f[8];
        if (k0 + 8 <= EE) {
            f32x4 x0 = *(const f32x4*)src;
            f32x4 x1 = *(const f32x4*)(src + 4);
            f[0]=x0[0]; f[1]=x0[1]; f[2]=x0[2]; f[3]=x0[3];
            f[4]=x1[0]; f[5]=x1[1]; f[6]=x1[2]; f[7]=x1[3];
        } else {
#pragma unroll
            for (int j = 0; j < 8; ++j) f[j] = (k0 + j < EE) ? src[j] : 0.f;
        }
        short8 v;
#pragma unroll
        for (int j = 0; j < 8; ++j) v[j] = (short)f2bf(f[j]);
        *(short8*)(WTB + (size_t)idx * 8) = v;
    } else if (idx < PW + PU) {
        int o = idx - PW;
        int lane = o & 63, r = o >> 6;
        int kk = r & 7, n = r >> 3;
        int g = n * 16 + (lane & 15);
        int k0 = kk * 32 + ((lane >> 4) << 3);
        const float* src = U + (size_t)g * K2 + k0;
        f32x4 x0 = *(const f32x4*)src;
        f32x4 x1 = *(const f32x4*)(src + 4);
        short8 v;
        v[0]=(short)f2bf(x0[0]); v[1]=(short)f2bf(x0[1]); v[2]=(short)f2bf(x0[2]); v[3]=(short)f2bf(x0[3]);
        v[4]=(short)f2bf(x1[0]); v[5]=(short)f2bf(x1[1]); v[6]=(short)f2bf(x1[2]); v[7]=(short)f2bf(x1[3]);
        *(short8*)(UTB + (size_t)o * 8) = v;
    }
}

// ---------------------------------------------------------------------------
// Main fused kernel: 128 blocks x 1024 threads; one (chart,batch) pair per
// block. The ENTIRE chart lives in LDS as bf16 (127 x 256, 544 B row stride).
// __launch_bounds__(1024, 4): 1 block/CU, 128-VGPR budget -> NO scratch spill
// (round-5's 64-VGPR cap spilled ~400 B/thread = 52 MB of HBM write traffic).
// ---------------------------------------------------------------------------
__global__ void __launch_bounds__(1024, 4) main_kernel(
        const int* __restrict__ sent1, const int* __restrict__ sent2,
        const int* __restrict__ ops1, const int* __restrict__ ops2,
        const int* __restrict__ oopl1, const int* __restrict__ oopl2,
        const short* __restrict__ WTB, const short* __restrict__ UTB,
        const float* __restrict__ bias, const float* __restrict__ eu,
        const float* __restrict__ invt,
        const float* __restrict__ unk, const float* __restrict__ wemb,
        float* __restrict__ fin) {
    __shared__ __align__(16) short chartL[127 * CROW + 16];   // 69.1 KiB bf16 chart
    __shared__ __align__(16) char  buf[40960];   // leaf A-frags 40K / step A-frags 16K + chh
    __shared__ int ops_all[SS * 64];             // 16.1 KiB (liveness + step gathers)
    __shared__ int sent_lds[64];
    __shared__ unsigned long long smask[64];
    __shared__ int live_list[SS];
    __shared__ float e_num[AMB], h2s[AMB], s_w[AMB];
    __shared__ float comb[2][2][HH];
    __shared__ int nl_sh;
    __shared__ float un_sh;

    short8* AsL = (short8*)buf;                  // leaf: 4 mt x 10 kk x 64
    short8* As2 = (short8*)buf;                  // step: 2 mt x 8 kk x 64
    float*  chh = (float*)(buf + 16384);         // step: 32 x 132 f32

    const int tid = threadIdx.x;
    const int pair = blockIdx.x, ch = pair >> 6, b = pair & 63;
    const int* sent = ch ? sent2 : sent1;
    const int* ops  = ch ? ops2 : ops1;
    const int* oopl = ch ? oopl2 : oopl1;
    const float it = invt[0];
    const int w = tid >> 6, lane = tid & 63, quad = lane >> 4, l15 = lane & 15;

    // ---- A0: cooperative loads (all parallel, no dependent chains) ----
#pragma unroll
    for (int i = 0; i < 4; ++i) {
        int idx = i * 1024 + tid;
        if (idx < SS * 64) ops_all[idx] = min(max(ops[b * SS * 64 + idx], 0), PP - 1);
    }
    if (tid < 64) sent_lds[tid] = sent[b * LL + tid];
    if (tid < 64) {
        float v = eu[tid] * eu[tid] + eu[tid + 64] * eu[tid + 64];
        for (int off = 32; off >= 1; off >>= 1) v += __shfl_xor(v, off);
        if (tid == 0) un_sh = fmaxf(sqrtf(v), 1e-8f);
    }
    __syncthreads();

    // ---- A1: per-step candidate masks (16 waves x up to 4 steps) ----
#pragma unroll
    for (int i = 0; i < 4; ++i) {
        int t = i * 16 + w;
        if (t < SS) {
            int q = ops_all[t * 64 + lane] - LL;
            unsigned long long bit = (q >= 0 && q < t) ? (1ull << q) : 0ull;
            for (int off = 32; off >= 1; off >>= 1) bit |= __shfl_xor(bit, off);
            if (lane == 0) smask[t] = bit;
        }
    }
    __syncthreads();

    // ---- A2: serial closure (LDS-only, ~62 iters) by thread 0 ----
    if (tid == 0) {
        unsigned long long mask = 0ull;
        int q0 = oopl[b] - 1 - LL;
        if (q0 >= 0) { if (q0 > SS - 1) q0 = SS - 1; mask = 1ull << q0; }
        for (int t = SS - 1; t >= 1; --t)
            if ((mask >> t) & 1) mask |= smask[t];
        int n = 0;
        for (int t = 0; t < SS; ++t)
            if ((mask >> t) & 1) live_list[n++] = t;
        nl_sh = n;
    }

    // ---- B: zero step rows; gather embeddings -> leaf A-frags ----
#pragma unroll
    for (int i = 0; i < 3; ++i) {
        int idx = i * 1024 + tid;
        if (idx < 2142)   // 63 rows x 272 shorts = 2142 int4
            ((int4*)(chartL + 64 * CROW))[idx] = make_int4(0, 0, 0, 0);
    }
    // per-slot: load 32 B -> convert -> LDS. Short live range (no spill).
    for (int i = 0; i < 3; ++i) {
        int slot = i * 1024 + tid;            // 2560 = 64 tok x 40 k-octets
        if (slot < 2560) {
            int t = slot / 40, oct = slot - t * 40;
            int s = sent_lds[t];
            const float* src = (s >= 0) ? (wemb + (size_t)s * EE) : unk;
            int k0 = oct * 8;
            short8 v;
            if (k0 + 8 <= EE) {
                f32x4 x0 = *(const f32x4*)(src + k0);
                f32x4 x1 = *(const f32x4*)(src + k0 + 4);
                v[0]=(short)f2bf(x0[0]); v[1]=(short)f2bf(x0[1]);
                v[2]=(short)f2bf(x0[2]); v[3]=(short)f2bf(x0[3]);
                v[4]=(short)f2bf(x1[0]); v[5]=(short)f2bf(x1[1]);
                v[6]=(short)f2bf(x1[2]); v[7]=(short)f2bf(x1[3]);
            } else {
#pragma unroll
                for (int j = 0; j < 8; ++j)
                    v[j] = (short)f2bf((k0 + j < EE) ? src[k0 + j] : 0.f);
            }
            AsL[((t >> 4) * 10 + (oct >> 2)) * 64 + ((oct & 3) << 4) + (t & 15)] = v;
        }
    }
    __syncthreads();

    // ---- leaf GEMM: 16 waves = 4 Mtiles x 4 nu-groups; gates i,o,u ----
    {
        const int mt = w & 3, nug = w >> 2;
        f32x4 acc[2][3] = {};
        for (int kk = 0; kk < 10; ++kk) {
            short8 a0 = AsL[(mt * 10 + kk) * 64 + lane];
#pragma unroll
            for (int si = 0; si < 3; ++si) {
                int s5 = (si == 0) ? 0 : (si == 1 ? 3 : 4);
#pragma unroll
                for (int hf = 0; hf < 2; ++hf) {
                    int n = (nug + hf * 4) + 8 * s5;
                    short8 bv = *(const short8*)(WTB + ((size_t)(n * 10 + kk) * 64 + lane) * 8);
                    acc[hf][si] = __builtin_amdgcn_mfma_f32_16x16x32_bf16(a0, bv, acc[hf][si], 0, 0, 0);
                }
            }
        }
#pragma unroll
        for (int hf = 0; hf < 2; ++hf) {
            int jc = (nug + hf * 4) * 16 + l15;
            float bi = bias[jc], bo = bias[3 * HH + jc], bu = bias[4 * HH + jc];
#pragma unroll
            for (int r = 0; r < 4; ++r) {
                float pi = acc[hf][0][r] + bi;
                float po = acc[hf][1][r] + bo;
                float pu = acc[hf][2][r] + bu;
                float cv = sigf(pi) * tanhf(pu);
                float hv = sigf(po) * tanhf(cv);
                int l = mt * 16 + quad * 4 + r;
                chartL[l * CROW + jc]      = (short)f2bf(cv);
                chartL[l * CROW + HH + jc] = (short)f2bf(hv);
            }
        }
    }
    __syncthreads();

    // ---- C: live steps (all LDS) ----
    const int nl = nl_sh;
    const float eul = eu[lane], euh = eu[64 + lane];
    const int smt = w & 1, snu = w >> 1;
    const int sjc = snu * 16 + l15;
    const float bi  = bias[sjc],          bfl = bias[HH + sjc];
    const float bfr = bias[2 * HH + sjc], bo  = bias[3 * HH + sjc];
    const float bu  = bias[4 * HH + sjc];

    for (int sidx = 0; sidx < nl; ++sidx) {
        const int t = live_list[sidx];
        const int* oprow = ops_all + t * 64;

        // gather h -> step A-frags (pure LDS->LDS b128, no conversion)
        {
            int a = tid >> 5, oct = tid & 31, side = oct >> 4, m8 = oct & 15;
            int row = oprow[2 * a + side];
            short8 v = *(const short8*)(chartL + row * CROW + HH + m8 * 8);
            As2[((a >> 4) * 8 + (oct >> 2)) * 64 + ((oct & 3) << 4) + (a & 15)] = v;
        }
        __syncthreads();

        float cvals[4], hvals[4];
        {
            f32x4 acc[5] = {};
            for (int kk = 0; kk < 8; ++kk) {
                short8 a0 = As2[(smt * 8 + kk) * 64 + lane];
#pragma unroll
                for (int s5 = 0; s5 < 5; ++s5) {
                    short8 bv = *(const short8*)(UTB + ((size_t)((snu + 8 * s5) * 8 + kk) * 64 + lane) * 8);
                    acc[s5] = __builtin_amdgcn_mfma_f32_16x16x32_bf16(a0, bv, acc[s5], 0, 0, 0);
                }
            }
#pragma unroll
            for (int r = 0; r < 4; ++r) {
                int a = smt * 16 + quad * 4 + r;
                float ccLv = bf2f(chartL[oprow[2 * a] * CROW + sjc]);
                float ccRv = bf2f(chartL[oprow[2 * a + 1] * CROW + sjc]);
                float cv = sigf(acc[1][r] + bfl) * ccLv
                         + sigf(acc[2][r] + bfr) * ccRv
                         + sigf(acc[0][r] + bi) * tanhf(acc[4][r] + bu);
                float hv = sigf(acc[3][r] + bo) * tanhf(cv);
                cvals[r] = cv; hvals[r] = hv;
                chh[a * 132 + sjc] = hv;
            }
        }
        __syncthreads();

        // energy per candidate (16 waves x 2 cands)
#pragma unroll
        for (int i = 0; i < 2; ++i) {
            int a = w * 2 + i;
            float h0 = chh[a * 132 + lane], h1 = chh[a * 132 + 64 + lane];
            float pe = h0 * eul + h1 * euh;
            float pn = h0 * h0 + h1 * h1;
            for (int off = 32; off >= 1; off >>= 1) {
                pe += __shfl_xor(pe, off);
                pn += __shfl_xor(pn, off);
            }
            if (lane == 0) { e_num[a] = pe; h2s[a] = pn; }
        }
        __syncthreads();

        // softmax over 32 candidates (wave 0)
        if (tid < 64) {
            float v = (tid < AMB)
                ? (e_num[tid] / (fmaxf(sqrtf(h2s[tid]), 1e-8f) * un_sh)) * it
                : -3.4e38f;
            float m = v;
            for (int off = 32; off >= 1; off >>= 1) m = fmaxf(m, __shfl_xor(m, off));
            float ex = (tid < AMB) ? __expf(v - m) : 0.f;
            float su = ex;
            for (int off = 32; off >= 1; off >>= 1) su += __shfl_xor(su, off);
            if (tid < AMB) s_w[tid] = ex / su;
        }
        __syncthreads();

        // combine from registers, reduce across quads, write chart row L+t
        {
            float sc = 0.f, sh = 0.f;
#pragma unroll
            for (int r = 0; r < 4; ++r) {
                int a = smt * 16 + quad * 4 + r;
                float sw = s_w[a];
                sc = fmaf(sw, cvals[r], sc);
                sh = fmaf(sw, hvals[r], sh);
            }
            sc += __shfl_xor(sc, 16); sc += __shfl_xor(sc, 32);
            sh += __shfl_xor(sh, 16); sh += __shfl_xor(sh, 32);
            if (lane < 16) {
                comb[smt][0][sjc] = sc;
                comb[smt][1][sjc] = sh;
            }
        }
        __syncthreads();
        if (tid < K2) {
            int part = tid >> 7, col = tid & 127;
            float val = comb[0][part][col] + comb[1][part][col];
            chartL[(LL + t) * CROW + part * HH + col] = (short)f2bf(val);
        }
        __syncthreads();
    }

    // ---- final readout row -> global ----
    int p = min(max(oopl[b] - 1, 0), PP - 1);
    if (tid < K2)
        fin[(size_t)pair * K2 + tid] = bf2f(chartL[p * CROW + tid]);
}

// ---------------------------------------------------------------------------
// MLP readout: 256 blocks = 16 j-tiles x 16 b-tiles (4 batch rows each).
// ---------------------------------------------------------------------------
__global__ void __launch_bounds__(256) mlp_kernel(
        const float* __restrict__ fin,
        const float* __restrict__ A, const float* __restrict__ abias,
        float* __restrict__ out) {
    __shared__ __align__(16) float conc[4][512];
    const int tid = threadIdx.x;
    const int jt = blockIdx.x & 15, bt = blockIdx.x >> 4;

#pragma unroll
    for (int i = 0; i < 2; ++i) {
        int s = i * 256 + tid;                // 512 vec4 slots = 4 b x 128
        int bl = s >> 7, kv = s & 127;
        int k0 = kv * 4, sel = k0 >> 7, kk0 = k0 & 127;
        int b = bt * 4 + bl;
        f32x4 s1 = *(const f32x4*)(fin + (size_t)b * K2 + HH + kk0);
        f32x4 s2 = *(const f32x4*)(fin + (size_t)(BSZ + b) * K2 + HH + kk0);
        f32x4 v;
        if (sel == 0)      { f32x4 d = s1 - s2; v = d * d; }
        else if (sel == 1) v = s1 * s2;
        else if (sel == 2) v = s1;
        else               v = s2;
        *(f32x4*)&conc[bl][k0] = v;
    }
    __syncthreads();

    const int jj = tid & 63, bg = tid >> 6;
    const int j = jt * 64 + jj, b = bt * 4 + bg;
    const float* Arow = A + (size_t)j * 512;
    float acc0 = abias[j], acc1 = 0.f;
    for (int k = 0; k < 512; k += 8) {
        f32x4 a0 = *(const f32x4*)(Arow + k);
        f32x4 a1 = *(const f32x4*)(Arow + k + 4);
        f32x4 c0 = *(const f32x4*)&conc[bg][k];
        f32x4 c1 = *(const f32x4*)&conc[bg][k + 4];
#pragma unroll
        for (int u = 0; u < 4; ++u) {
            acc0 = fmaf(a0[u], c0[u], acc0);
            acc1 = fmaf(a1[u], c1[u], acc1);
        }
    }
    out[(size_t)b * MLPN + j] = fmaxf(acc0 + acc1, 0.f);
}

// ---------------------------------------------------------------------------
extern "C" void kernel_launch(void* const* d_in, const int* in_sizes, int n_in,
                              void* d_out, int out_size, void* d_ws, size_t ws_size,
                              hipStream_t stream) {
    const int*   sent1 = (const int*)d_in[0];
    const int*   ops1  = (const int*)d_in[1];
    const int*   oopl1 = (const int*)d_in[2];
    const int*   sent2 = (const int*)d_in[3];
    const int*   ops2  = (const int*)d_in[4];
    const int*   oopl2 = (const int*)d_in[5];
    const float* W     = (const float*)d_in[6];
    const float* U     = (const float*)d_in[7];
    const float* bias  = (const float*)d_in[8];
    const float* eu    = (const float*)d_in[9];
    const float* unk   = (const float*)d_in[10];
    const float* wemb  = (const float*)d_in[11];
    const float* A     = (const float*)d_in[12];
    const float* ab    = (const float*)d_in[13];
    const float* invt  = (const float*)d_in[14];
    float* out = (float*)d_out;
    (void)in_sizes; (void)n_in; (void)out_size; (void)ws_size;

    char* ws = (char*)d_ws;
    // ws layout (bytes):
    const size_t WTB_OFF = 0;          // 204800*2 = 409,600
    const size_t UTB_OFF = 409600;     // 163840*2 = 327,680
    const size_t FIN_OFF = 737280;     // 128*256*4 = 131,072
    short* WTB = (short*)(ws + WTB_OFF);
    short* UTB = (short*)(ws + UTB_OFF);
    float* fin = (float*)(ws + FIN_OFF);

    // prep: (PW+PU)/256 = 180 blocks
    prep_kernel<<<180, 256, 0, stream>>>(W, U, WTB, UTB);

    main_kernel<<<128, 1024, 0, stream>>>(sent1, sent2, ops1, ops2, oopl1, oopl2,
                                          WTB, UTB, bias, eu, invt, unk, wemb, fin);

    mlp_kernel<<<256, 256, 0, stream>>>(fin, A, ab, out);
}